// Round 2
// baseline (555.189 us; speedup 1.0000x reference)
//
#include <hip/hip_runtime.h>
#include <hip/hip_fp16.h>
#include <hip/hip_bf16.h>

constexpr int BB  = 8;
constexpr int NN  = 4096;
constexpr int CC  = 256;
constexpr int CKK = 32;

typedef __attribute__((ext_vector_type(8))) short    short8;  // 8 x bf16 bits
typedef __attribute__((ext_vector_type(8))) _Float16 half8;
typedef __attribute__((ext_vector_type(4))) _Float16 half4;
typedef __attribute__((ext_vector_type(4))) float    f32x4;

__device__ __forceinline__ unsigned short bf16_bits(float v) {
    __hip_bfloat16 h = __float2bfloat16(v);
    return *reinterpret_cast<unsigned short*>(&h);
}
__device__ __forceinline__ float bf16_val(unsigned short u) {
    __hip_bfloat16 h = *reinterpret_cast<__hip_bfloat16*>(&u);
    return __bfloat162float(h);
}

// ---------------------------------------------------------------------------
// K0: transpose + bf16 hi/lo split of all weights into WT[576][256]:
// rows 0..255 = Wh cols, 256..287 = Wf, 288..319 = Wg, 320..575 = Wo.
// ---------------------------------------------------------------------------
__global__ __launch_bounds__(256) void prep_kernel(
    const float* __restrict__ Wf, const float* __restrict__ Wg,
    const float* __restrict__ Wh, const float* __restrict__ Wo,
    unsigned short* __restrict__ WThi, unsigned short* __restrict__ WTlo)
{
    const int n = blockIdx.x;
    const int k = threadIdx.x;
    float v;
    if      (n < 256) v = Wh[k * 256 + n];
    else if (n < 288) v = Wf[k * 32 + (n - 256)];
    else if (n < 320) v = Wg[k * 32 + (n - 288)];
    else              v = Wo[k * 256 + (n - 320)];
    const unsigned short hi = bf16_bits(v);
    WThi[n * 256 + k] = hi;
    WTlo[n * 256 + k] = bf16_bits(v - bf16_val(hi));
}

// ---------------------------------------------------------------------------
// K1: projections as tiled GEMM [32768 x 256] @ [256 x 320].
// Block = 128 M x 64 N (grid 256 x 5) -> 1280 blocks = 5/CU (was 2.5/CU:
// grid-limited latency stall). Wave = 32M x 64N = 8 acc tiles.
// nb 0..3: hh channels -> fp16 transposed hhT[b][c][n] (plain layout).
// nb 4: f (nt 0,1) and g (nt 2,3) -> fp16 [n][d].
// ---------------------------------------------------------------------------
__global__ __launch_bounds__(256) void fgh_kernel(
    const float* __restrict__ x,
    const unsigned short* __restrict__ WThi, const unsigned short* __restrict__ WTlo,
    const float* __restrict__ bf, const float* __restrict__ bg,
    const float* __restrict__ bh,
    _Float16* __restrict__ fbuf, _Float16* __restrict__ gbuf,
    _Float16* __restrict__ hhT)
{
    const int tid = threadIdx.x, w = tid >> 6, lane = tid & 63;
    const int ln = lane & 15, lq = lane >> 4;
    const int px0 = blockIdx.x * 128 + w * 32;   // this wave's first pixel
    const int n0  = blockIdx.y * 64;             // output-column base (0..256)

    f32x4 acc[2][4];   // [mt][nt]
    #pragma unroll
    for (int i = 0; i < 2; ++i)
        #pragma unroll
        for (int j = 0; j < 4; ++j) acc[i][j] = {0.f, 0.f, 0.f, 0.f};

    #pragma unroll 1
    for (int kc = 0; kc < 8; ++kc) {
        const int k0 = kc * 32;
        short8 Ahi[2], Alo[2];
        #pragma unroll
        for (int mt = 0; mt < 2; ++mt) {
            float av[8];
            const float* xp = &x[(size_t)(px0 + mt * 16 + ln) * CC + k0 + lq * 8];
            *(float4*)&av[0] = *(const float4*)xp;
            *(float4*)&av[4] = *(const float4*)(xp + 4);
            #pragma unroll
            for (int j = 0; j < 8; ++j) {
                const unsigned short h = bf16_bits(av[j]);
                Ahi[mt][j] = (short)h;
                Alo[mt][j] = (short)bf16_bits(av[j] - bf16_val(h));
            }
        }
        #pragma unroll
        for (int nt = 0; nt < 4; ++nt) {
            const size_t boff = (size_t)(n0 + nt * 16 + ln) * 256 + k0 + lq * 8;
            const short8 Bhi = *(const short8*)&WThi[boff];
            const short8 Blo = *(const short8*)&WTlo[boff];
            #pragma unroll
            for (int mt = 0; mt < 2; ++mt) {
                acc[mt][nt] = __builtin_amdgcn_mfma_f32_16x16x32_bf16(Ahi[mt], Bhi, acc[mt][nt], 0, 0, 0);
                acc[mt][nt] = __builtin_amdgcn_mfma_f32_16x16x32_bf16(Ahi[mt], Blo, acc[mt][nt], 0, 0, 0);
                acc[mt][nt] = __builtin_amdgcn_mfma_f32_16x16x32_bf16(Alo[mt], Bhi, acc[mt][nt], 0, 0, 0);
            }
        }
    }

    const int b = px0 >> 12;
    if (blockIdx.y < 4) {
        // hh channels n0..n0+63 -> transposed fp16 store
        #pragma unroll
        for (int nt = 0; nt < 4; ++nt) {
            const int c = n0 + nt * 16 + ln;
            const float bias = bh[c];
            #pragma unroll
            for (int mt = 0; mt < 2; ++mt) {
                half4 hv;
                #pragma unroll
                for (int r = 0; r < 4; ++r) hv[r] = (_Float16)(acc[mt][nt][r] + bias);
                const int npix = (px0 & (NN - 1)) + mt * 16 + lq * 4;
                *(half4*)&hhT[((size_t)(b * CC + c)) * NN + npix] = hv;
            }
        }
    } else {
        // f (nt 0,1), g (nt 2,3): d = (nt&1)*16 + ln
        #pragma unroll
        for (int nt = 0; nt < 4; ++nt) {
            const int d = (nt & 1) * 16 + ln;
            const float bias = (nt < 2) ? bf[d] : bg[d];
            _Float16* dst = (nt < 2) ? fbuf : gbuf;
            #pragma unroll
            for (int mt = 0; mt < 2; ++mt)
                #pragma unroll
                for (int r = 0; r < 4; ++r)
                    dst[(size_t)(px0 + mt * 16 + lq * 4 + r) * CKK + d] =
                        (_Float16)(acc[mt][nt][r] + bias);
        }
    }
}

// ---------------------------------------------------------------------------
// K2: MFMA flash attention, shared-P structure, all-K32.
// Block = 64 q x 128 c of one batch (blockIdx.y = channel half); 4 waves.
// Grid 512 x 2 = 1024 blocks -> 4 blocks/CU (was 2: grid-capped at 22%
// occupancy with both pipes <31% busy = latency-bound). The channel split
// duplicates only phase A (4 MFMA + exp per wave-iter); PV (8x the MFMA
// volume) is partitioned, not duplicated.
// Per 64-key iter:
//   phase A: wave w computes S^T for ITS 16 keys x 64 q (4 MFMA, no dup),
//            exp -> fp16 P -> shared LDS tile (A-layout, pad-72, dbuf)
//   barrier (1/iter)
//   phase B: issue NEXT iter's Bh global loads (post-barrier), then PV
//            with THIS iter's Bh (double-buffered in registers),
//            wave covers 32 channels.
// Rowmax pass-1 identical-instruction trick keeps exp <= 1 (fp16-safe).
// ---------------------------------------------------------------------------
__global__ __launch_bounds__(256, 4) void attn_kernel(
    const _Float16* __restrict__ fbuf, const _Float16* __restrict__ gbuf,
    const _Float16* __restrict__ hhT, float* __restrict__ obuf)
{
    __shared__ _Float16 P[2][64 * 72];   // 18 KB, dbuf
    __shared__ float mxbuf[4][64];
    __shared__ float rsbuf[4][64];

    const int tid = threadIdx.x, w = tid >> 6, lane = tid & 63;
    const int ln = lane & 15, lq = lane >> 4;
    const int b  = blockIdx.x & 7;               // batch == XCD
    const int q0 = (blockIdx.x >> 3) * 64;
    const int cb = blockIdx.y * 128 + w * 32;    // this wave's channel base

    const f32x4 zero = {0.f, 0.f, 0.f, 0.f};
    constexpr float LOG2E = 1.4426950408889634f;

    // persistent g B-frags: B[k=d][n=q]
    half8 Bg[4];
    #pragma unroll
    for (int qt = 0; qt < 4; ++qt)
        Bg[qt] = *(const half8*)&gbuf[(size_t)(b * NN + q0 + qt * 16 + ln) * CKK + lq * 8];

    // base pointers (advance by constants inside loops)
    const _Float16* fb = &fbuf[(size_t)(b * NN + w * 16 + ln) * CKK + lq * 8];
    const _Float16* hb = &hhT[((size_t)(b * CC + cb + ln)) * NN + lq * 8];

    // ---- pass 1: rowmax (wave w covers keys j0 + w*16 + 0..15), pipelined ----
    float mx[4];
    #pragma unroll
    for (int qt = 0; qt < 4; ++qt) mx[qt] = -1e30f;
    half8 Afc = *(const half8*)fb;
    #pragma unroll 1
    for (int j0 = 0; j0 < NN; j0 += 64) {
        const int jn = (j0 + 64 < NN) ? j0 + 64 : j0;
        const half8 Afn = *(const half8*)&fb[(size_t)jn * CKK];
        #pragma unroll
        for (int qt = 0; qt < 4; ++qt) {
            const f32x4 s = __builtin_amdgcn_mfma_f32_16x16x32_f16(Afc, Bg[qt], zero, 0, 0, 0);
            mx[qt] = fmaxf(mx[qt], fmaxf(fmaxf(s[0], s[1]), fmaxf(s[2], s[3])));
        }
        Afc = Afn;
    }
    #pragma unroll
    for (int qt = 0; qt < 4; ++qt) {
        mx[qt] = fmaxf(mx[qt], __shfl_xor(mx[qt], 16));
        mx[qt] = fmaxf(mx[qt], __shfl_xor(mx[qt], 32));
    }
    if (lane < 16) {
        #pragma unroll
        for (int qt = 0; qt < 4; ++qt) mxbuf[w][qt * 16 + ln] = mx[qt];
    }
    __syncthreads();
    float mk[4];   // per-lane: q = qt*16 + ln
    #pragma unroll
    for (int qt = 0; qt < 4; ++qt)
        mk[qt] = LOG2E * fmaxf(fmaxf(mxbuf[0][qt * 16 + ln], mxbuf[1][qt * 16 + ln]),
                               fmaxf(mxbuf[2][qt * 16 + ln], mxbuf[3][qt * 16 + ln]));

    // ---- main loop ----
    f32x4 O[4][2];     // [qt][ct]
    #pragma unroll
    for (int qt = 0; qt < 4; ++qt)
        #pragma unroll
        for (int ct = 0; ct < 2; ++ct) O[qt][ct] = zero;
    float psum[4] = {0.f, 0.f, 0.f, 0.f};

    // phase A: S^T -> exp -> P (LDS); identical MFMA to pass 1
    auto phaseA = [&](const half8& Af, _Float16* Pb) {
        #pragma unroll
        for (int qt = 0; qt < 4; ++qt) {
            const f32x4 s = __builtin_amdgcn_mfma_f32_16x16x32_f16(Af, Bg[qt], zero, 0, 0, 0);
            half4 ph;
            float ps = 0.f;
            #pragma unroll
            for (int r = 0; r < 4; ++r) {
                const float p = exp2f(fmaf(s[r], LOG2E, -mk[qt]));
                ps += p;
                ph[r] = (_Float16)p;
            }
            psum[qt] += ps;
            // P[q = qt*16+ln][key = w*16 + lq*4 + r]  (A-layout, pad 72)
            *(half4*)&Pb[(qt * 16 + ln) * 72 + w * 16 + lq * 4] = ph;
        }
    };

    // issue 4 global b128 loads of hhT B-frags for key block j0
    auto loadBh = [&](half8 (&Bh)[2][2], int j0) {
        #pragma unroll
        for (int ct = 0; ct < 2; ++ct)
            #pragma unroll
            for (int kh = 0; kh < 2; ++kh)
                Bh[ct][kh] = *(const half8*)&hb[(size_t)ct * 16 * NN + j0 + kh * 32];
    };

    // phase B: PV for this wave's 32 channels, K=64 via 2 K32 halves
    auto phaseB = [&](const half8 (&Bh)[2][2], const _Float16* Pb) {
        __builtin_amdgcn_s_setprio(1);
        #pragma unroll
        for (int qt = 0; qt < 4; ++qt) {
            const half8 Ap0 = *(const half8*)&Pb[(qt * 16 + ln) * 72 + lq * 8];
            const half8 Ap1 = *(const half8*)&Pb[(qt * 16 + ln) * 72 + 32 + lq * 8];
            #pragma unroll
            for (int ct = 0; ct < 2; ++ct) {
                O[qt][ct] = __builtin_amdgcn_mfma_f32_16x16x32_f16(Ap0, Bh[ct][0], O[qt][ct], 0, 0, 0);
                O[qt][ct] = __builtin_amdgcn_mfma_f32_16x16x32_f16(Ap1, Bh[ct][1], O[qt][ct], 0, 0, 0);
            }
        }
        __builtin_amdgcn_s_setprio(0);
    };

    // prologue: current-iter buffers
    half8 Bh0[2][2], Bh1[2][2];
    half8 Af0, Af1;
    loadBh(Bh0, 0);
    Af0 = *(const half8*)fb;

    #pragma unroll 1
    for (int j0 = 0; j0 < NN; j0 += 128) {
        // --- even 64-key block: uses Bh0/Af0, prefetches Bh1/Af1 ---
        phaseA(Af0, P[0]);
        __syncthreads();                         // drains Bh0 (issued 1 iter ago)
        loadBh(Bh1, j0 + 64);                    // post-barrier issue: lands during
        Af1 = *(const half8*)&fb[(size_t)(j0 + 64) * CKK];  // phaseB + next phaseA
        phaseB(Bh0, P[0]);
        // --- odd 64-key block: uses Bh1/Af1, prefetches Bh0/Af0 ---
        phaseA(Af1, P[1]);
        __syncthreads();
        if (j0 + 128 < NN) {
            loadBh(Bh0, j0 + 128);
            Af0 = *(const half8*)&fb[(size_t)(j0 + 128) * CKK];
        }
        phaseB(Bh1, P[1]);
    }

    // ---- rowsum merge across waves ----
    #pragma unroll
    for (int qt = 0; qt < 4; ++qt) {
        psum[qt] += __shfl_xor(psum[qt], 16);
        psum[qt] += __shfl_xor(psum[qt], 32);
    }
    if (lane < 16) {
        #pragma unroll
        for (int qt = 0; qt < 4; ++qt) rsbuf[w][qt * 16 + ln] = psum[qt];
    }
    __syncthreads();

    // ---- epilogue: normalize, store (row-indexed q) ----
    #pragma unroll
    for (int qt = 0; qt < 4; ++qt)
        #pragma unroll
        for (int r = 0; r < 4; ++r) {
            const int q = qt * 16 + lq * 4 + r;
            const float rinv = 1.0f / (rsbuf[0][q] + rsbuf[1][q] + rsbuf[2][q] + rsbuf[3][q]);
            #pragma unroll
            for (int ct = 0; ct < 2; ++ct)
                obuf[((size_t)(b * NN + q0 + q)) * CC + cb + ct * 16 + ln] = O[qt][ct][r] * rinv;
        }
}

// ---------------------------------------------------------------------------
// K3: out = gamma * (o @ Wo + bo) + x  as tiled GEMM [32768x256]@[256x256].
// Block = 128 M (grid 256 x 4) -> 1024 blocks = 4/CU, same occupancy fix.
// ---------------------------------------------------------------------------
__global__ __launch_bounds__(256) void out_kernel(
    const float* __restrict__ obuf,
    const unsigned short* __restrict__ WThi, const unsigned short* __restrict__ WTlo,
    const float* __restrict__ bo, const float* __restrict__ gamma,
    const float* __restrict__ x, float* __restrict__ out)
{
    const int tid = threadIdx.x, w = tid >> 6, lane = tid & 63;
    const int ln = lane & 15, lq = lane >> 4;
    const int px0 = blockIdx.x * 128 + w * 32;
    const int n0  = blockIdx.y * 64;

    f32x4 acc[2][4];
    #pragma unroll
    for (int i = 0; i < 2; ++i)
        #pragma unroll
        for (int j = 0; j < 4; ++j) acc[i][j] = {0.f, 0.f, 0.f, 0.f};

    #pragma unroll 1
    for (int kc = 0; kc < 8; ++kc) {
        const int k0 = kc * 32;
        short8 Ahi[2], Alo[2];
        #pragma unroll
        for (int mt = 0; mt < 2; ++mt) {
            float av[8];
            const float* op = &obuf[(size_t)(px0 + mt * 16 + ln) * CC + k0 + lq * 8];
            *(float4*)&av[0] = *(const float4*)op;
            *(float4*)&av[4] = *(const float4*)(op + 4);
            #pragma unroll
            for (int j = 0; j < 8; ++j) {
                const unsigned short h = bf16_bits(av[j]);
                Ahi[mt][j] = (short)h;
                Alo[mt][j] = (short)bf16_bits(av[j] - bf16_val(h));
            }
        }
        #pragma unroll
        for (int nt = 0; nt < 4; ++nt) {
            const size_t boff = (size_t)(320 + n0 + nt * 16 + ln) * 256 + k0 + lq * 8;
            const short8 Bhi = *(const short8*)&WThi[boff];
            const short8 Blo = *(const short8*)&WTlo[boff];
            #pragma unroll
            for (int mt = 0; mt < 2; ++mt) {
                acc[mt][nt] = __builtin_amdgcn_mfma_f32_16x16x32_bf16(Ahi[mt], Bhi, acc[mt][nt], 0, 0, 0);
                acc[mt][nt] = __builtin_amdgcn_mfma_f32_16x16x32_bf16(Ahi[mt], Blo, acc[mt][nt], 0, 0, 0);
                acc[mt][nt] = __builtin_amdgcn_mfma_f32_16x16x32_bf16(Alo[mt], Bhi, acc[mt][nt], 0, 0, 0);
            }
        }
    }

    const float gm = gamma[0];
    #pragma unroll
    for (int nt = 0; nt < 4; ++nt) {
        const int c = n0 + nt * 16 + ln;
        const float bias = bo[c];
        #pragma unroll
        for (int mt = 0; mt < 2; ++mt)
            #pragma unroll
            for (int r = 0; r < 4; ++r) {
                const size_t idx = (size_t)(px0 + mt * 16 + lq * 4 + r) * CC + c;
                out[idx] = gm * (acc[mt][nt][r] + bias) + x[idx];
            }
    }
}

// ---------------------------------------------------------------------------
extern "C" void kernel_launch(void* const* d_in, const int* in_sizes, int n_in,
                              void* d_out, int out_size, void* d_ws, size_t ws_size,
                              hipStream_t stream)
{
    (void)in_sizes; (void)n_in; (void)out_size; (void)ws_size;

    const float* x     = (const float*)d_in[0];
    const float* Wf    = (const float*)d_in[1];
    const float* bf    = (const float*)d_in[2];
    const float* Wg    = (const float*)d_in[3];
    const float* bg    = (const float*)d_in[4];
    const float* Wh    = (const float*)d_in[5];
    const float* bh    = (const float*)d_in[6];
    const float* Wo    = (const float*)d_in[7];
    const float* bo    = (const float*)d_in[8];
    const float* gamma = (const float*)d_in[9];
    float* out = (float*)d_out;

    // ws: f(2MB) | g(2MB) | hhT(16MB) | o(32MB) | WThi | WTlo (~0.6MB)
    _Float16* fbuf = (_Float16*)d_ws;
    _Float16* gbuf = fbuf + (size_t)BB * NN * CKK;
    _Float16* hhT  = gbuf + (size_t)BB * NN * CKK;
    float*    obuf = (float*)(hhT + (size_t)BB * CC * NN);
    unsigned short* WThi = (unsigned short*)(obuf + (size_t)BB * NN * CC);
    unsigned short* WTlo = WThi + (size_t)576 * 256;

    prep_kernel<<<576, 256, 0, stream>>>(Wf, Wg, Wh, Wo, WThi, WTlo);
    fgh_kernel<<<dim3(BB * NN / 128, 5), 256, 0, stream>>>(x, WThi, WTlo, bf, bg, bh,
                                                           fbuf, gbuf, hhT);
    attn_kernel<<<dim3(BB * NN / 64, 2), 256, 0, stream>>>(fbuf, gbuf, hhT, obuf);
    out_kernel<<<dim3(BB * NN / 128, 4), 256, 0, stream>>>(obuf, WThi, WTlo, bo, gamma, x, out);
}

// Round 3
// 396.121 us; speedup vs baseline: 1.4016x; 1.4016x over previous
//
#include <hip/hip_runtime.h>
#include <hip/hip_fp16.h>
#include <hip/hip_bf16.h>

constexpr int BB  = 8;
constexpr int NN  = 4096;
constexpr int CC  = 256;
constexpr int CKK = 32;

typedef __attribute__((ext_vector_type(8))) short    short8;  // 8 x bf16 bits
typedef __attribute__((ext_vector_type(8))) _Float16 half8;
typedef __attribute__((ext_vector_type(4))) _Float16 half4;
typedef __attribute__((ext_vector_type(4))) float    f32x4;

__device__ __forceinline__ unsigned short bf16_bits(float v) {
    __hip_bfloat16 h = __float2bfloat16(v);
    return *reinterpret_cast<unsigned short*>(&h);
}
__device__ __forceinline__ float bf16_val(unsigned short u) {
    __hip_bfloat16 h = *reinterpret_cast<__hip_bfloat16*>(&u);
    return __bfloat162float(h);
}

// ---------------------------------------------------------------------------
// K0: transpose + bf16 hi/lo split of all weights into WT[576][256]:
// rows 0..255 = Wh cols, 256..287 = Wf, 288..319 = Wg, 320..575 = Wo.
// ---------------------------------------------------------------------------
__global__ __launch_bounds__(256) void prep_kernel(
    const float* __restrict__ Wf, const float* __restrict__ Wg,
    const float* __restrict__ Wh, const float* __restrict__ Wo,
    unsigned short* __restrict__ WThi, unsigned short* __restrict__ WTlo)
{
    const int n = blockIdx.x;
    const int k = threadIdx.x;
    float v;
    if      (n < 256) v = Wh[k * 256 + n];
    else if (n < 288) v = Wf[k * 32 + (n - 256)];
    else if (n < 320) v = Wg[k * 32 + (n - 288)];
    else              v = Wo[k * 256 + (n - 320)];
    const unsigned short hi = bf16_bits(v);
    WThi[n * 256 + k] = hi;
    WTlo[n * 256 + k] = bf16_bits(v - bf16_val(hi));
}

// ---------------------------------------------------------------------------
// K1: projections as tiled GEMM [32768 x 256] @ [256 x 320].
// Block = 256 M x 64 N (grid 128 x 5); wave = 64M x 64N = 16 acc tiles.
// (256-M tile: the 128-M split was a measured net loss -- doubled B-panel
// re-reads for the GEMMs.)
// nb 0..3: hh channels -> fp16 transposed hhT[b][c][n] (plain layout).
// nb 4: f (nt 0,1) and g (nt 2,3) -> fp16 [n][d].
// ---------------------------------------------------------------------------
__global__ __launch_bounds__(256) void fgh_kernel(
    const float* __restrict__ x,
    const unsigned short* __restrict__ WThi, const unsigned short* __restrict__ WTlo,
    const float* __restrict__ bf, const float* __restrict__ bg,
    const float* __restrict__ bh,
    _Float16* __restrict__ fbuf, _Float16* __restrict__ gbuf,
    _Float16* __restrict__ hhT)
{
    const int tid = threadIdx.x, w = tid >> 6, lane = tid & 63;
    const int ln = lane & 15, lq = lane >> 4;
    const int px0 = blockIdx.x * 256 + w * 64;   // this wave's first pixel
    const int n0  = blockIdx.y * 64;             // output-column base (0..256)

    f32x4 acc[4][4];   // [mt][nt]
    #pragma unroll
    for (int i = 0; i < 4; ++i)
        #pragma unroll
        for (int j = 0; j < 4; ++j) acc[i][j] = {0.f, 0.f, 0.f, 0.f};

    #pragma unroll 1
    for (int kc = 0; kc < 8; ++kc) {
        const int k0 = kc * 32;
        short8 Ahi[4], Alo[4];
        #pragma unroll
        for (int mt = 0; mt < 4; ++mt) {
            float av[8];
            const float* xp = &x[(size_t)(px0 + mt * 16 + ln) * CC + k0 + lq * 8];
            *(float4*)&av[0] = *(const float4*)xp;
            *(float4*)&av[4] = *(const float4*)(xp + 4);
            #pragma unroll
            for (int j = 0; j < 8; ++j) {
                const unsigned short h = bf16_bits(av[j]);
                Ahi[mt][j] = (short)h;
                Alo[mt][j] = (short)bf16_bits(av[j] - bf16_val(h));
            }
        }
        #pragma unroll
        for (int nt = 0; nt < 4; ++nt) {
            const size_t boff = (size_t)(n0 + nt * 16 + ln) * 256 + k0 + lq * 8;
            const short8 Bhi = *(const short8*)&WThi[boff];
            const short8 Blo = *(const short8*)&WTlo[boff];
            #pragma unroll
            for (int mt = 0; mt < 4; ++mt) {
                acc[mt][nt] = __builtin_amdgcn_mfma_f32_16x16x32_bf16(Ahi[mt], Bhi, acc[mt][nt], 0, 0, 0);
                acc[mt][nt] = __builtin_amdgcn_mfma_f32_16x16x32_bf16(Ahi[mt], Blo, acc[mt][nt], 0, 0, 0);
                acc[mt][nt] = __builtin_amdgcn_mfma_f32_16x16x32_bf16(Alo[mt], Bhi, acc[mt][nt], 0, 0, 0);
            }
        }
    }

    const int b = px0 >> 12;
    if (blockIdx.y < 4) {
        // hh channels n0..n0+63 -> transposed fp16 store
        #pragma unroll
        for (int nt = 0; nt < 4; ++nt) {
            const int c = n0 + nt * 16 + ln;
            const float bias = bh[c];
            #pragma unroll
            for (int mt = 0; mt < 4; ++mt) {
                half4 hv;
                #pragma unroll
                for (int r = 0; r < 4; ++r) hv[r] = (_Float16)(acc[mt][nt][r] + bias);
                const int npix = (px0 & (NN - 1)) + mt * 16 + lq * 4;
                *(half4*)&hhT[((size_t)(b * CC + c)) * NN + npix] = hv;
            }
        }
    } else {
        // f (nt 0,1), g (nt 2,3): d = (nt&1)*16 + ln
        #pragma unroll
        for (int nt = 0; nt < 4; ++nt) {
            const int d = (nt & 1) * 16 + ln;
            const float bias = (nt < 2) ? bf[d] : bg[d];
            _Float16* dst = (nt < 2) ? fbuf : gbuf;
            #pragma unroll
            for (int mt = 0; mt < 4; ++mt)
                #pragma unroll
                for (int r = 0; r < 4; ++r)
                    dst[(size_t)(px0 + mt * 16 + lq * 4 + r) * CKK + d] =
                        (_Float16)(acc[mt][nt][r] + bias);
        }
    }
}

// ---------------------------------------------------------------------------
// K2: MFMA flash attention, shared-P structure, all-K32.
// Block = 64 q x 128 c of one batch (blockIdx.y = channel half); 4 waves.
// Grid 512 x 2 = 1024 blocks -> 4 blocks/CU. Channel split duplicates only
// phase A (4 MFMA + exp per wave-iter); PV is partitioned, not duplicated.
// __launch_bounds__(256, 2): on this toolchain the waves-per-EU arg is
// budgeted 2x for wave64 -> (256,4) capped VGPR at 64 and spilled 1.2 GB
// of scratch to HBM (round-2 regression). (256,2) -> 128-VGPR budget;
// working set ~105 regs fits, HW then allows 4 blocks/CU from the grid.
// Per 64-key iter:
//   phase A: wave w computes S^T for ITS 16 keys x 64 q (4 MFMA, no dup),
//            exp -> fp16 P -> shared LDS tile (A-layout, pad-72, dbuf)
//   barrier (1/iter)
//   phase B: issue NEXT iter's Bh global loads (post-barrier), then PV
//            with THIS iter's Bh (register dbuf), wave covers 32 channels.
// Rowmax pass-1 identical-instruction trick keeps exp <= 1 (fp16-safe).
// ---------------------------------------------------------------------------
__global__ __launch_bounds__(256, 2) void attn_kernel(
    const _Float16* __restrict__ fbuf, const _Float16* __restrict__ gbuf,
    const _Float16* __restrict__ hhT, float* __restrict__ obuf)
{
    __shared__ _Float16 P[2][64 * 72];   // 18 KB, dbuf
    __shared__ float mxbuf[4][64];
    __shared__ float rsbuf[4][64];

    const int tid = threadIdx.x, w = tid >> 6, lane = tid & 63;
    const int ln = lane & 15, lq = lane >> 4;
    const int b  = blockIdx.x & 7;               // batch == XCD
    const int q0 = (blockIdx.x >> 3) * 64;
    const int cb = blockIdx.y * 128 + w * 32;    // this wave's channel base

    const f32x4 zero = {0.f, 0.f, 0.f, 0.f};
    constexpr float LOG2E = 1.4426950408889634f;

    // persistent g B-frags: B[k=d][n=q]
    half8 Bg[4];
    #pragma unroll
    for (int qt = 0; qt < 4; ++qt)
        Bg[qt] = *(const half8*)&gbuf[(size_t)(b * NN + q0 + qt * 16 + ln) * CKK + lq * 8];

    // base pointers (advance by constants inside loops)
    const _Float16* fb = &fbuf[(size_t)(b * NN + w * 16 + ln) * CKK + lq * 8];
    const _Float16* hb = &hhT[((size_t)(b * CC + cb + ln)) * NN + lq * 8];

    // ---- pass 1: rowmax (wave w covers keys j0 + w*16 + 0..15), pipelined ----
    float mx[4];
    #pragma unroll
    for (int qt = 0; qt < 4; ++qt) mx[qt] = -1e30f;
    half8 Afc = *(const half8*)fb;
    #pragma unroll 1
    for (int j0 = 0; j0 < NN; j0 += 64) {
        const int jn = (j0 + 64 < NN) ? j0 + 64 : j0;
        const half8 Afn = *(const half8*)&fb[(size_t)jn * CKK];
        #pragma unroll
        for (int qt = 0; qt < 4; ++qt) {
            const f32x4 s = __builtin_amdgcn_mfma_f32_16x16x32_f16(Afc, Bg[qt], zero, 0, 0, 0);
            mx[qt] = fmaxf(mx[qt], fmaxf(fmaxf(s[0], s[1]), fmaxf(s[2], s[3])));
        }
        Afc = Afn;
    }
    #pragma unroll
    for (int qt = 0; qt < 4; ++qt) {
        mx[qt] = fmaxf(mx[qt], __shfl_xor(mx[qt], 16));
        mx[qt] = fmaxf(mx[qt], __shfl_xor(mx[qt], 32));
    }
    if (lane < 16) {
        #pragma unroll
        for (int qt = 0; qt < 4; ++qt) mxbuf[w][qt * 16 + ln] = mx[qt];
    }
    __syncthreads();
    float mk[4];   // per-lane: q = qt*16 + ln
    #pragma unroll
    for (int qt = 0; qt < 4; ++qt)
        mk[qt] = LOG2E * fmaxf(fmaxf(mxbuf[0][qt * 16 + ln], mxbuf[1][qt * 16 + ln]),
                               fmaxf(mxbuf[2][qt * 16 + ln], mxbuf[3][qt * 16 + ln]));

    // ---- main loop ----
    f32x4 O[4][2];     // [qt][ct]
    #pragma unroll
    for (int qt = 0; qt < 4; ++qt)
        #pragma unroll
        for (int ct = 0; ct < 2; ++ct) O[qt][ct] = zero;
    float psum[4] = {0.f, 0.f, 0.f, 0.f};

    // phase A: S^T -> exp -> P (LDS); identical MFMA to pass 1
    auto phaseA = [&](const half8& Af, _Float16* Pb) {
        #pragma unroll
        for (int qt = 0; qt < 4; ++qt) {
            const f32x4 s = __builtin_amdgcn_mfma_f32_16x16x32_f16(Af, Bg[qt], zero, 0, 0, 0);
            half4 ph;
            float ps = 0.f;
            #pragma unroll
            for (int r = 0; r < 4; ++r) {
                const float p = exp2f(fmaf(s[r], LOG2E, -mk[qt]));
                ps += p;
                ph[r] = (_Float16)p;
            }
            psum[qt] += ps;
            // P[q = qt*16+ln][key = w*16 + lq*4 + r]  (A-layout, pad 72)
            *(half4*)&Pb[(qt * 16 + ln) * 72 + w * 16 + lq * 4] = ph;
        }
    };

    // issue 4 global b128 loads of hhT B-frags for key block j0
    auto loadBh = [&](half8 (&Bh)[2][2], int j0) {
        #pragma unroll
        for (int ct = 0; ct < 2; ++ct)
            #pragma unroll
            for (int kh = 0; kh < 2; ++kh)
                Bh[ct][kh] = *(const half8*)&hb[(size_t)ct * 16 * NN + j0 + kh * 32];
    };

    // phase B: PV for this wave's 32 channels, K=64 via 2 K32 halves
    auto phaseB = [&](const half8 (&Bh)[2][2], const _Float16* Pb) {
        __builtin_amdgcn_s_setprio(1);
        #pragma unroll
        for (int qt = 0; qt < 4; ++qt) {
            const half8 Ap0 = *(const half8*)&Pb[(qt * 16 + ln) * 72 + lq * 8];
            const half8 Ap1 = *(const half8*)&Pb[(qt * 16 + ln) * 72 + 32 + lq * 8];
            #pragma unroll
            for (int ct = 0; ct < 2; ++ct) {
                O[qt][ct] = __builtin_amdgcn_mfma_f32_16x16x32_f16(Ap0, Bh[ct][0], O[qt][ct], 0, 0, 0);
                O[qt][ct] = __builtin_amdgcn_mfma_f32_16x16x32_f16(Ap1, Bh[ct][1], O[qt][ct], 0, 0, 0);
            }
        }
        __builtin_amdgcn_s_setprio(0);
    };

    // prologue: current-iter buffers
    half8 Bh0[2][2], Bh1[2][2];
    half8 Af0, Af1;
    loadBh(Bh0, 0);
    Af0 = *(const half8*)fb;

    #pragma unroll 1
    for (int j0 = 0; j0 < NN; j0 += 128) {
        // --- even 64-key block: uses Bh0/Af0, prefetches Bh1/Af1 ---
        phaseA(Af0, P[0]);
        __syncthreads();                         // drains Bh0 (issued 1 iter ago)
        loadBh(Bh1, j0 + 64);                    // post-barrier issue: lands during
        Af1 = *(const half8*)&fb[(size_t)(j0 + 64) * CKK];  // phaseB + next phaseA
        phaseB(Bh0, P[0]);
        // --- odd 64-key block: uses Bh1/Af1, prefetches Bh0/Af0 ---
        phaseA(Af1, P[1]);
        __syncthreads();
        if (j0 + 128 < NN) {
            loadBh(Bh0, j0 + 128);
            Af0 = *(const half8*)&fb[(size_t)(j0 + 128) * CKK];
        }
        phaseB(Bh1, P[1]);
    }

    // ---- rowsum merge across waves ----
    #pragma unroll
    for (int qt = 0; qt < 4; ++qt) {
        psum[qt] += __shfl_xor(psum[qt], 16);
        psum[qt] += __shfl_xor(psum[qt], 32);
    }
    if (lane < 16) {
        #pragma unroll
        for (int qt = 0; qt < 4; ++qt) rsbuf[w][qt * 16 + ln] = psum[qt];
    }
    __syncthreads();

    // ---- epilogue: normalize, store (row-indexed q) ----
    #pragma unroll
    for (int qt = 0; qt < 4; ++qt)
        #pragma unroll
        for (int r = 0; r < 4; ++r) {
            const int q = qt * 16 + lq * 4 + r;
            const float rinv = 1.0f / (rsbuf[0][q] + rsbuf[1][q] + rsbuf[2][q] + rsbuf[3][q]);
            #pragma unroll
            for (int ct = 0; ct < 2; ++ct)
                obuf[((size_t)(b * NN + q0 + q)) * CC + cb + ct * 16 + ln] = O[qt][ct][r] * rinv;
        }
}

// ---------------------------------------------------------------------------
// K3: out = gamma * (o @ Wo + bo) + x  as tiled GEMM [32768x256]@[256x256].
// Same structure as fgh_kernel, grid 128 x 4 (256-M tile).
// ---------------------------------------------------------------------------
__global__ __launch_bounds__(256) void out_kernel(
    const float* __restrict__ obuf,
    const unsigned short* __restrict__ WThi, const unsigned short* __restrict__ WTlo,
    const float* __restrict__ bo, const float* __restrict__ gamma,
    const float* __restrict__ x, float* __restrict__ out)
{
    const int tid = threadIdx.x, w = tid >> 6, lane = tid & 63;
    const int ln = lane & 15, lq = lane >> 4;
    const int px0 = blockIdx.x * 256 + w * 64;
    const int n0  = blockIdx.y * 64;

    f32x4 acc[4][4];
    #pragma unroll
    for (int i = 0; i < 4; ++i)
        #pragma unroll
        for (int j = 0; j < 4; ++j) acc[i][j] = {0.f, 0.f, 0.f, 0.f};

    #pragma unroll 1
    for (int kc = 0; kc < 8; ++kc) {
        const int k0 = kc * 32;
        short8 Ahi[4], Alo[4];
        #pragma unroll
        for (int mt = 0; mt < 4; ++mt) {
            float av[8];
            const float* op = &obuf[(size_t)(px0 + mt * 16 + ln) * CC + k0 + lq * 8];
            *(float4*)&av[0] = *(const float4*)op;
            *(float4*)&av[4] = *(const float4*)(op + 4);
            #pragma unroll
            for (int j = 0; j < 8; ++j) {
                const unsigned short h = bf16_bits(av[j]);
                Ahi[mt][j] = (short)h;
                Alo[mt][j] = (short)bf16_bits(av[j] - bf16_val(h));
            }
        }
        #pragma unroll
        for (int nt = 0; nt < 4; ++nt) {
            const size_t boff = (size_t)(320 + n0 + nt * 16 + ln) * 256 + k0 + lq * 8;
            const short8 Bhi = *(const short8*)&WThi[boff];
            const short8 Blo = *(const short8*)&WTlo[boff];
            #pragma unroll
            for (int mt = 0; mt < 4; ++mt) {
                acc[mt][nt] = __builtin_amdgcn_mfma_f32_16x16x32_bf16(Ahi[mt], Bhi, acc[mt][nt], 0, 0, 0);
                acc[mt][nt] = __builtin_amdgcn_mfma_f32_16x16x32_bf16(Ahi[mt], Blo, acc[mt][nt], 0, 0, 0);
                acc[mt][nt] = __builtin_amdgcn_mfma_f32_16x16x32_bf16(Alo[mt], Bhi, acc[mt][nt], 0, 0, 0);
            }
        }
    }

    const float gm = gamma[0];
    #pragma unroll
    for (int nt = 0; nt < 4; ++nt) {
        const int c = n0 + nt * 16 + ln;
        const float bias = bo[c];
        #pragma unroll
        for (int mt = 0; mt < 4; ++mt)
            #pragma unroll
            for (int r = 0; r < 4; ++r) {
                const size_t idx = (size_t)(px0 + mt * 16 + lq * 4 + r) * CC + c;
                out[idx] = gm * (acc[mt][nt][r] + bias) + x[idx];
            }
    }
}

// ---------------------------------------------------------------------------
extern "C" void kernel_launch(void* const* d_in, const int* in_sizes, int n_in,
                              void* d_out, int out_size, void* d_ws, size_t ws_size,
                              hipStream_t stream)
{
    (void)in_sizes; (void)n_in; (void)out_size; (void)ws_size;

    const float* x     = (const float*)d_in[0];
    const float* Wf    = (const float*)d_in[1];
    const float* bf    = (const float*)d_in[2];
    const float* Wg    = (const float*)d_in[3];
    const float* bg    = (const float*)d_in[4];
    const float* Wh    = (const float*)d_in[5];
    const float* bh    = (const float*)d_in[6];
    const float* Wo    = (const float*)d_in[7];
    const float* bo    = (const float*)d_in[8];
    const float* gamma = (const float*)d_in[9];
    float* out = (float*)d_out;

    // ws: f(2MB) | g(2MB) | hhT(16MB) | o(32MB) | WThi | WTlo (~0.6MB)
    _Float16* fbuf = (_Float16*)d_ws;
    _Float16* gbuf = fbuf + (size_t)BB * NN * CKK;
    _Float16* hhT  = gbuf + (size_t)BB * NN * CKK;
    float*    obuf = (float*)(hhT + (size_t)BB * CC * NN);
    unsigned short* WThi = (unsigned short*)(obuf + (size_t)BB * NN * CC);
    unsigned short* WTlo = WThi + (size_t)576 * 256;

    prep_kernel<<<576, 256, 0, stream>>>(Wf, Wg, Wh, Wo, WThi, WTlo);
    fgh_kernel<<<dim3(BB * NN / 256, 5), 256, 0, stream>>>(x, WThi, WTlo, bf, bg, bh,
                                                           fbuf, gbuf, hhT);
    attn_kernel<<<dim3(BB * NN / 64, 2), 256, 0, stream>>>(fbuf, gbuf, hhT, obuf);
    out_kernel<<<dim3(BB * NN / 256, 4), 256, 0, stream>>>(obuf, WThi, WTlo, bo, gamma, x, out);
}

// Round 4
// 342.560 us; speedup vs baseline: 1.6207x; 1.1564x over previous
//
#include <hip/hip_runtime.h>
#include <hip/hip_fp16.h>
#include <hip/hip_bf16.h>

constexpr int BB  = 8;
constexpr int NN  = 4096;
constexpr int CC  = 256;
constexpr int CKK = 32;

typedef __attribute__((ext_vector_type(8))) short    short8;  // 8 x bf16 bits
typedef __attribute__((ext_vector_type(8))) _Float16 half8;
typedef __attribute__((ext_vector_type(4))) _Float16 half4;
typedef __attribute__((ext_vector_type(4))) float    f32x4;

__device__ __forceinline__ unsigned short bf16_bits(float v) {
    __hip_bfloat16 h = __float2bfloat16(v);
    return *reinterpret_cast<unsigned short*>(&h);
}
__device__ __forceinline__ float bf16_val(unsigned short u) {
    __hip_bfloat16 h = *reinterpret_cast<__hip_bfloat16*>(&u);
    return __bfloat162float(h);
}

// ---------------------------------------------------------------------------
// K0: transpose + bf16 hi/lo split of all weights into WT[576][256]:
// rows 0..255 = Wh cols, 256..287 = Wf, 288..319 = Wg, 320..575 = Wo.
// ---------------------------------------------------------------------------
__global__ __launch_bounds__(256) void prep_kernel(
    const float* __restrict__ Wf, const float* __restrict__ Wg,
    const float* __restrict__ Wh, const float* __restrict__ Wo,
    unsigned short* __restrict__ WThi, unsigned short* __restrict__ WTlo)
{
    const int n = blockIdx.x;
    const int k = threadIdx.x;
    float v;
    if      (n < 256) v = Wh[k * 256 + n];
    else if (n < 288) v = Wf[k * 32 + (n - 256)];
    else if (n < 320) v = Wg[k * 32 + (n - 288)];
    else              v = Wo[k * 256 + (n - 320)];
    const unsigned short hi = bf16_bits(v);
    WThi[n * 256 + k] = hi;
    WTlo[n * 256 + k] = bf16_bits(v - bf16_val(hi));
}

// ---------------------------------------------------------------------------
// K0b: split x (f32, 32 MB) into bf16 hi/lo planes ONCE. fgh previously
// re-converted the same A-rows in-register for each of its 5 N-blocks
// (~160 VALU ops/k-step/wave > the 48 MFMAs); this hoists all of it.
// Memory-bound: ~64 MB of traffic ~= 12 us.
// ---------------------------------------------------------------------------
__global__ __launch_bounds__(256) void splitx_kernel(
    const float* __restrict__ x,
    unsigned short* __restrict__ xhi, unsigned short* __restrict__ xlo)
{
    const size_t total  = (size_t)BB * NN * CC;
    const size_t stride = (size_t)gridDim.x * 256 * 8;
    for (size_t i = ((size_t)blockIdx.x * 256 + threadIdx.x) * 8; i < total; i += stride) {
        float av[8];
        *(float4*)&av[0] = *(const float4*)&x[i];
        *(float4*)&av[4] = *(const float4*)&x[i + 4];
        short8 hi, lo;
        #pragma unroll
        for (int j = 0; j < 8; ++j) {
            const unsigned short h = bf16_bits(av[j]);
            hi[j] = (short)h;
            lo[j] = (short)bf16_bits(av[j] - bf16_val(h));
        }
        *(short8*)&xhi[i] = hi;
        *(short8*)&xlo[i] = lo;
    }
}

// ---------------------------------------------------------------------------
// K1: projections as tiled GEMM [32768 x 256] @ [256 x 320].
// Block = 256 M x 64 N (grid 128 x 5); wave = 64M x 64N = 16 acc tiles.
// A-operand now loaded directly from pre-split xhi/xlo (short8) -- no
// per-k-step conversion VALU. MFMA order identical -> bitwise-same output.
// nb 0..3: hh channels -> fp16 transposed hhT[b][c][n] (plain layout).
// nb 4: f (nt 0,1) and g (nt 2,3) -> fp16 [n][d].
// ---------------------------------------------------------------------------
__global__ __launch_bounds__(256) void fgh_kernel(
    const unsigned short* __restrict__ xhi, const unsigned short* __restrict__ xlo,
    const unsigned short* __restrict__ WThi, const unsigned short* __restrict__ WTlo,
    const float* __restrict__ bf, const float* __restrict__ bg,
    const float* __restrict__ bh,
    _Float16* __restrict__ fbuf, _Float16* __restrict__ gbuf,
    _Float16* __restrict__ hhT)
{
    const int tid = threadIdx.x, w = tid >> 6, lane = tid & 63;
    const int ln = lane & 15, lq = lane >> 4;
    const int px0 = blockIdx.x * 256 + w * 64;   // this wave's first pixel
    const int n0  = blockIdx.y * 64;             // output-column base (0..256)

    f32x4 acc[4][4];   // [mt][nt]
    #pragma unroll
    for (int i = 0; i < 4; ++i)
        #pragma unroll
        for (int j = 0; j < 4; ++j) acc[i][j] = {0.f, 0.f, 0.f, 0.f};

    #pragma unroll 1
    for (int kc = 0; kc < 8; ++kc) {
        const int k0 = kc * 32;
        short8 Ahi[4], Alo[4];
        #pragma unroll
        for (int mt = 0; mt < 4; ++mt) {
            const size_t aoff = (size_t)(px0 + mt * 16 + ln) * CC + k0 + lq * 8;
            Ahi[mt] = *(const short8*)&xhi[aoff];
            Alo[mt] = *(const short8*)&xlo[aoff];
        }
        #pragma unroll
        for (int nt = 0; nt < 4; ++nt) {
            const size_t boff = (size_t)(n0 + nt * 16 + ln) * 256 + k0 + lq * 8;
            const short8 Bhi = *(const short8*)&WThi[boff];
            const short8 Blo = *(const short8*)&WTlo[boff];
            #pragma unroll
            for (int mt = 0; mt < 4; ++mt) {
                acc[mt][nt] = __builtin_amdgcn_mfma_f32_16x16x32_bf16(Ahi[mt], Bhi, acc[mt][nt], 0, 0, 0);
                acc[mt][nt] = __builtin_amdgcn_mfma_f32_16x16x32_bf16(Ahi[mt], Blo, acc[mt][nt], 0, 0, 0);
                acc[mt][nt] = __builtin_amdgcn_mfma_f32_16x16x32_bf16(Alo[mt], Bhi, acc[mt][nt], 0, 0, 0);
            }
        }
    }

    const int b = px0 >> 12;
    if (blockIdx.y < 4) {
        // hh channels n0..n0+63 -> transposed fp16 store
        #pragma unroll
        for (int nt = 0; nt < 4; ++nt) {
            const int c = n0 + nt * 16 + ln;
            const float bias = bh[c];
            #pragma unroll
            for (int mt = 0; mt < 4; ++mt) {
                half4 hv;
                #pragma unroll
                for (int r = 0; r < 4; ++r) hv[r] = (_Float16)(acc[mt][nt][r] + bias);
                const int npix = (px0 & (NN - 1)) + mt * 16 + lq * 4;
                *(half4*)&hhT[((size_t)(b * CC + c)) * NN + npix] = hv;
            }
        }
    } else {
        // f (nt 0,1), g (nt 2,3): d = (nt&1)*16 + ln
        #pragma unroll
        for (int nt = 0; nt < 4; ++nt) {
            const int d = (nt & 1) * 16 + ln;
            const float bias = (nt < 2) ? bf[d] : bg[d];
            _Float16* dst = (nt < 2) ? fbuf : gbuf;
            #pragma unroll
            for (int mt = 0; mt < 4; ++mt)
                #pragma unroll
                for (int r = 0; r < 4; ++r)
                    dst[(size_t)(px0 + mt * 16 + lq * 4 + r) * CKK + d] =
                        (_Float16)(acc[mt][nt][r] + bias);
        }
    }
}

// ---------------------------------------------------------------------------
// K2: MFMA flash attention -- EXACT round-1 structure (measured 160.7 us,
// VGPR 108, the best configuration found; channel/q splits regressed).
// Block = 64 q x 256 c of one batch; 4 waves. Per 64-key iter:
//   phase A: wave w computes S^T for ITS 16 keys x 64 q (4 MFMA, no dup),
//            exp -> fp16 P -> shared LDS tile (A-layout, pad-72, dbuf)
//   barrier (1/iter)
//   phase B: issue NEXT iter's Bh global loads (post-barrier), then PV
//            with THIS iter's Bh (register dbuf).
// Epilogue change only: store o as bf16 hi/lo planes (same split math the
// out_kernel used to do inline, 4x redundantly) -- bitwise-identical.
// ---------------------------------------------------------------------------
__global__ __launch_bounds__(256, 2) void attn_kernel(
    const _Float16* __restrict__ fbuf, const _Float16* __restrict__ gbuf,
    const _Float16* __restrict__ hhT,
    unsigned short* __restrict__ ohi, unsigned short* __restrict__ olo)
{
    __shared__ _Float16 P[2][64 * 72];   // 18 KB, dbuf
    __shared__ float mxbuf[4][64];
    __shared__ float rsbuf[4][64];

    const int tid = threadIdx.x, w = tid >> 6, lane = tid & 63;
    const int ln = lane & 15, lq = lane >> 4;
    const int b  = blockIdx.x & 7;               // batch == XCD
    const int q0 = (blockIdx.x >> 3) * 64;
    const int cb = w * 64;                       // this wave's channel base

    const f32x4 zero = {0.f, 0.f, 0.f, 0.f};
    constexpr float LOG2E = 1.4426950408889634f;

    // persistent g B-frags: B[k=d][n=q]
    half8 Bg[4];
    #pragma unroll
    for (int qt = 0; qt < 4; ++qt)
        Bg[qt] = *(const half8*)&gbuf[(size_t)(b * NN + q0 + qt * 16 + ln) * CKK + lq * 8];

    // base pointers (advance by constants inside loops)
    const _Float16* fb = &fbuf[(size_t)(b * NN + w * 16 + ln) * CKK + lq * 8];
    const _Float16* hb = &hhT[((size_t)(b * CC + cb + ln)) * NN + lq * 8];

    // ---- pass 1: rowmax (wave w covers keys j0 + w*16 + 0..15), pipelined ----
    float mx[4];
    #pragma unroll
    for (int qt = 0; qt < 4; ++qt) mx[qt] = -1e30f;
    half8 Afc = *(const half8*)fb;
    #pragma unroll 1
    for (int j0 = 0; j0 < NN; j0 += 64) {
        const int jn = (j0 + 64 < NN) ? j0 + 64 : j0;
        const half8 Afn = *(const half8*)&fb[(size_t)jn * CKK];
        #pragma unroll
        for (int qt = 0; qt < 4; ++qt) {
            const f32x4 s = __builtin_amdgcn_mfma_f32_16x16x32_f16(Afc, Bg[qt], zero, 0, 0, 0);
            mx[qt] = fmaxf(mx[qt], fmaxf(fmaxf(s[0], s[1]), fmaxf(s[2], s[3])));
        }
        Afc = Afn;
    }
    #pragma unroll
    for (int qt = 0; qt < 4; ++qt) {
        mx[qt] = fmaxf(mx[qt], __shfl_xor(mx[qt], 16));
        mx[qt] = fmaxf(mx[qt], __shfl_xor(mx[qt], 32));
    }
    if (lane < 16) {
        #pragma unroll
        for (int qt = 0; qt < 4; ++qt) mxbuf[w][qt * 16 + ln] = mx[qt];
    }
    __syncthreads();
    float mk[4];   // per-lane: q = qt*16 + ln
    #pragma unroll
    for (int qt = 0; qt < 4; ++qt)
        mk[qt] = LOG2E * fmaxf(fmaxf(mxbuf[0][qt * 16 + ln], mxbuf[1][qt * 16 + ln]),
                               fmaxf(mxbuf[2][qt * 16 + ln], mxbuf[3][qt * 16 + ln]));

    // ---- main loop ----
    f32x4 O[4][4];     // [qt][ct]
    #pragma unroll
    for (int qt = 0; qt < 4; ++qt)
        #pragma unroll
        for (int ct = 0; ct < 4; ++ct) O[qt][ct] = zero;
    float psum[4] = {0.f, 0.f, 0.f, 0.f};

    // phase A: S^T -> exp -> P (LDS); identical MFMA to pass 1
    auto phaseA = [&](const half8& Af, _Float16* Pb) {
        #pragma unroll
        for (int qt = 0; qt < 4; ++qt) {
            const f32x4 s = __builtin_amdgcn_mfma_f32_16x16x32_f16(Af, Bg[qt], zero, 0, 0, 0);
            half4 ph;
            float ps = 0.f;
            #pragma unroll
            for (int r = 0; r < 4; ++r) {
                const float p = exp2f(fmaf(s[r], LOG2E, -mk[qt]));
                ps += p;
                ph[r] = (_Float16)p;
            }
            psum[qt] += ps;
            // P[q = qt*16+ln][key = w*16 + lq*4 + r]  (A-layout, pad 72)
            *(half4*)&Pb[(qt * 16 + ln) * 72 + w * 16 + lq * 4] = ph;
        }
    };

    // issue 8 global b128 loads of hhT B-frags for key block j0
    auto loadBh = [&](half8 (&Bh)[4][2], int j0) {
        #pragma unroll
        for (int ct = 0; ct < 4; ++ct)
            #pragma unroll
            for (int kh = 0; kh < 2; ++kh)
                Bh[ct][kh] = *(const half8*)&hb[(size_t)ct * 16 * NN + j0 + kh * 32];
    };

    // phase B: PV for this wave's 64 channels, K=64 via 2 K32 halves
    auto phaseB = [&](const half8 (&Bh)[4][2], const _Float16* Pb) {
        __builtin_amdgcn_s_setprio(1);
        #pragma unroll
        for (int qt = 0; qt < 4; ++qt) {
            const half8 Ap0 = *(const half8*)&Pb[(qt * 16 + ln) * 72 + lq * 8];
            const half8 Ap1 = *(const half8*)&Pb[(qt * 16 + ln) * 72 + 32 + lq * 8];
            #pragma unroll
            for (int ct = 0; ct < 4; ++ct) {
                O[qt][ct] = __builtin_amdgcn_mfma_f32_16x16x32_f16(Ap0, Bh[ct][0], O[qt][ct], 0, 0, 0);
                O[qt][ct] = __builtin_amdgcn_mfma_f32_16x16x32_f16(Ap1, Bh[ct][1], O[qt][ct], 0, 0, 0);
            }
        }
        __builtin_amdgcn_s_setprio(0);
    };

    // prologue: current-iter buffers
    half8 Bh0[4][2], Bh1[4][2];
    half8 Af0, Af1;
    loadBh(Bh0, 0);
    Af0 = *(const half8*)fb;

    #pragma unroll 1
    for (int j0 = 0; j0 < NN; j0 += 128) {
        // --- even 64-key block: uses Bh0/Af0, prefetches Bh1/Af1 ---
        phaseA(Af0, P[0]);
        __syncthreads();                         // drains Bh0 (issued 1 iter ago)
        loadBh(Bh1, j0 + 64);                    // post-barrier issue: lands during
        Af1 = *(const half8*)&fb[(size_t)(j0 + 64) * CKK];  // phaseB + next phaseA
        phaseB(Bh0, P[0]);
        // --- odd 64-key block: uses Bh1/Af1, prefetches Bh0/Af0 ---
        phaseA(Af1, P[1]);
        __syncthreads();
        if (j0 + 128 < NN) {
            loadBh(Bh0, j0 + 128);
            Af0 = *(const half8*)&fb[(size_t)(j0 + 128) * CKK];
        }
        phaseB(Bh1, P[1]);
    }

    // ---- rowsum merge across waves ----
    #pragma unroll
    for (int qt = 0; qt < 4; ++qt) {
        psum[qt] += __shfl_xor(psum[qt], 16);
        psum[qt] += __shfl_xor(psum[qt], 32);
    }
    if (lane < 16) {
        #pragma unroll
        for (int qt = 0; qt < 4; ++qt) rsbuf[w][qt * 16 + ln] = psum[qt];
    }
    __syncthreads();

    // ---- epilogue: normalize, split to bf16 hi/lo, store (row-indexed q) ----
    #pragma unroll
    for (int qt = 0; qt < 4; ++qt)
        #pragma unroll
        for (int r = 0; r < 4; ++r) {
            const int q = qt * 16 + lq * 4 + r;
            const float rinv = 1.0f / (rsbuf[0][q] + rsbuf[1][q] + rsbuf[2][q] + rsbuf[3][q]);
            #pragma unroll
            for (int ct = 0; ct < 4; ++ct) {
                const size_t idx = ((size_t)(b * NN + q0 + q)) * CC + cb + ct * 16 + ln;
                const float v = O[qt][ct][r] * rinv;
                const unsigned short h = bf16_bits(v);
                ohi[idx] = h;
                olo[idx] = bf16_bits(v - bf16_val(h));
            }
        }
}

// ---------------------------------------------------------------------------
// K3: out = gamma * (o @ Wo + bo) + x  as tiled GEMM [32768x256]@[256x256].
// A-operand from pre-split ohi/olo (written by attn epilogue) -- no inline
// conversion. Same MFMA order -> bitwise-identical. Grid 128 x 4.
// ---------------------------------------------------------------------------
__global__ __launch_bounds__(256) void out_kernel(
    const unsigned short* __restrict__ ohi, const unsigned short* __restrict__ olo,
    const unsigned short* __restrict__ WThi, const unsigned short* __restrict__ WTlo,
    const float* __restrict__ bo, const float* __restrict__ gamma,
    const float* __restrict__ x, float* __restrict__ out)
{
    const int tid = threadIdx.x, w = tid >> 6, lane = tid & 63;
    const int ln = lane & 15, lq = lane >> 4;
    const int px0 = blockIdx.x * 256 + w * 64;
    const int n0  = blockIdx.y * 64;

    f32x4 acc[4][4];
    #pragma unroll
    for (int i = 0; i < 4; ++i)
        #pragma unroll
        for (int j = 0; j < 4; ++j) acc[i][j] = {0.f, 0.f, 0.f, 0.f};

    #pragma unroll 1
    for (int kc = 0; kc < 8; ++kc) {
        const int k0 = kc * 32;
        short8 Ahi[4], Alo[4];
        #pragma unroll
        for (int mt = 0; mt < 4; ++mt) {
            const size_t aoff = (size_t)(px0 + mt * 16 + ln) * CC + k0 + lq * 8;
            Ahi[mt] = *(const short8*)&ohi[aoff];
            Alo[mt] = *(const short8*)&olo[aoff];
        }
        #pragma unroll
        for (int nt = 0; nt < 4; ++nt) {
            const size_t boff = (size_t)(320 + n0 + nt * 16 + ln) * 256 + k0 + lq * 8;
            const short8 Bhi = *(const short8*)&WThi[boff];
            const short8 Blo = *(const short8*)&WTlo[boff];
            #pragma unroll
            for (int mt = 0; mt < 4; ++mt) {
                acc[mt][nt] = __builtin_amdgcn_mfma_f32_16x16x32_bf16(Ahi[mt], Bhi, acc[mt][nt], 0, 0, 0);
                acc[mt][nt] = __builtin_amdgcn_mfma_f32_16x16x32_bf16(Ahi[mt], Blo, acc[mt][nt], 0, 0, 0);
                acc[mt][nt] = __builtin_amdgcn_mfma_f32_16x16x32_bf16(Alo[mt], Bhi, acc[mt][nt], 0, 0, 0);
            }
        }
    }

    const float gm = gamma[0];
    #pragma unroll
    for (int nt = 0; nt < 4; ++nt) {
        const int c = n0 + nt * 16 + ln;
        const float bias = bo[c];
        #pragma unroll
        for (int mt = 0; mt < 4; ++mt)
            #pragma unroll
            for (int r = 0; r < 4; ++r) {
                const size_t idx = (size_t)(px0 + mt * 16 + lq * 4 + r) * CC + c;
                out[idx] = gm * (acc[mt][nt][r] + bias) + x[idx];
            }
    }
}

// ---------------------------------------------------------------------------
extern "C" void kernel_launch(void* const* d_in, const int* in_sizes, int n_in,
                              void* d_out, int out_size, void* d_ws, size_t ws_size,
                              hipStream_t stream)
{
    (void)in_sizes; (void)n_in; (void)out_size; (void)ws_size;

    const float* x     = (const float*)d_in[0];
    const float* Wf    = (const float*)d_in[1];
    const float* bf    = (const float*)d_in[2];
    const float* Wg    = (const float*)d_in[3];
    const float* bg    = (const float*)d_in[4];
    const float* Wh    = (const float*)d_in[5];
    const float* bh    = (const float*)d_in[6];
    const float* Wo    = (const float*)d_in[7];
    const float* bo    = (const float*)d_in[8];
    const float* gamma = (const float*)d_in[9];
    float* out = (float*)d_out;

    // ws: f(2MB) | g(2MB) | hhT(16MB) | ohi(16MB) | olo(16MB) |
    //     xhi(16MB) | xlo(16MB) | WThi | WTlo (~0.6MB)   total ~85MB
    const size_t NP = (size_t)BB * NN;           // 32768 pixels
    _Float16* fbuf = (_Float16*)d_ws;
    _Float16* gbuf = fbuf + NP * CKK;
    _Float16* hhT  = gbuf + NP * CKK;
    unsigned short* ohi  = (unsigned short*)(hhT + NP * CC);
    unsigned short* olo  = ohi + NP * CC;
    unsigned short* xhi  = olo + NP * CC;
    unsigned short* xlo  = xhi + NP * CC;
    unsigned short* WThi = xlo + NP * CC;
    unsigned short* WTlo = WThi + (size_t)576 * 256;

    prep_kernel<<<576, 256, 0, stream>>>(Wf, Wg, Wh, Wo, WThi, WTlo);
    splitx_kernel<<<2048, 256, 0, stream>>>(x, xhi, xlo);
    fgh_kernel<<<dim3(BB * NN / 256, 5), 256, 0, stream>>>(xhi, xlo, WThi, WTlo, bf, bg, bh,
                                                           fbuf, gbuf, hhT);
    attn_kernel<<<BB * NN / 64, 256, 0, stream>>>(fbuf, gbuf, hhT, ohi, olo);
    out_kernel<<<dim3(BB * NN / 256, 4), 256, 0, stream>>>(ohi, olo, WThi, WTlo, bo, gamma, x, out);
}

// Round 5
// 324.816 us; speedup vs baseline: 1.7092x; 1.0546x over previous
//
#include <hip/hip_runtime.h>
#include <hip/hip_fp16.h>
#include <hip/hip_bf16.h>

constexpr int BB  = 8;
constexpr int NN  = 4096;
constexpr int CC  = 256;
constexpr int CKK = 32;

typedef __attribute__((ext_vector_type(8))) short    short8;  // 8 x bf16 bits
typedef __attribute__((ext_vector_type(8))) _Float16 half8;
typedef __attribute__((ext_vector_type(4))) _Float16 half4;
typedef __attribute__((ext_vector_type(4))) float    f32x4;

__device__ __forceinline__ unsigned short bf16_bits(float v) {
    __hip_bfloat16 h = __float2bfloat16(v);
    return *reinterpret_cast<unsigned short*>(&h);
}
__device__ __forceinline__ float bf16_val(unsigned short u) {
    __hip_bfloat16 h = *reinterpret_cast<__hip_bfloat16*>(&u);
    return __bfloat162float(h);
}

// ---------------------------------------------------------------------------
// K0: transpose + bf16 hi/lo split of all weights into WT[576][256]:
// rows 0..255 = Wh cols, 256..287 = Wf, 288..319 = Wg, 320..575 = Wo.
// ---------------------------------------------------------------------------
__global__ __launch_bounds__(256) void prep_kernel(
    const float* __restrict__ Wf, const float* __restrict__ Wg,
    const float* __restrict__ Wh, const float* __restrict__ Wo,
    unsigned short* __restrict__ WThi, unsigned short* __restrict__ WTlo)
{
    const int n = blockIdx.x;
    const int k = threadIdx.x;
    float v;
    if      (n < 256) v = Wh[k * 256 + n];
    else if (n < 288) v = Wf[k * 32 + (n - 256)];
    else if (n < 320) v = Wg[k * 32 + (n - 288)];
    else              v = Wo[k * 256 + (n - 320)];
    const unsigned short hi = bf16_bits(v);
    WThi[n * 256 + k] = hi;
    WTlo[n * 256 + k] = bf16_bits(v - bf16_val(hi));
}

// ---------------------------------------------------------------------------
// K1: projections as tiled GEMM [32768 x 256] @ [256 x 320].
// Block = 256 M x 64 N (grid 128 x 5); wave = 64M x 64N = 16 acc tiles.
// Software-pipelined k-loop (round-4 ruled out conversion VALU; the
// remaining structural stall was one full load latency per k-step):
//   per k-step: issue B(k) -> issue raw-A(k+1) prefetch -> convert A(k)
//   (~160 VALU ops cover B's L2 latency) -> 48 MFMAs (wait vmcnt(8),
//   the A-prefetch stays in flight across the MFMA block; never vmcnt(0)).
// Manual 2-phase unroll keeps rawA/rawB indices compile-time static.
// MFMA order per acc element identical to round-1 -> bitwise-same output.
// ---------------------------------------------------------------------------
__global__ __launch_bounds__(256) void fgh_kernel(
    const float* __restrict__ x,
    const unsigned short* __restrict__ WThi, const unsigned short* __restrict__ WTlo,
    const float* __restrict__ bf, const float* __restrict__ bg,
    const float* __restrict__ bh,
    _Float16* __restrict__ fbuf, _Float16* __restrict__ gbuf,
    _Float16* __restrict__ hhT)
{
    const int tid = threadIdx.x, w = tid >> 6, lane = tid & 63;
    const int ln = lane & 15, lq = lane >> 4;
    const int px0 = blockIdx.x * 256 + w * 64;   // this wave's first pixel
    const int n0  = blockIdx.y * 64;             // output-column base (0..256)

    f32x4 acc[4][4];   // [mt][nt]
    #pragma unroll
    for (int i = 0; i < 4; ++i)
        #pragma unroll
        for (int j = 0; j < 4; ++j) acc[i][j] = {0.f, 0.f, 0.f, 0.f};

    float  rawA[4][8], rawB[4][8];
    short8 Ahi[4], Alo[4], Bhi[4], Blo[4];

    auto loadraw = [&](float (&rw)[4][8], int k0) {
        #pragma unroll
        for (int mt = 0; mt < 4; ++mt) {
            const float* xp = &x[(size_t)(px0 + mt * 16 + ln) * CC + k0 + lq * 8];
            *(float4*)&rw[mt][0] = *(const float4*)xp;
            *(float4*)&rw[mt][4] = *(const float4*)(xp + 4);
        }
    };
    auto loadB = [&](int k0) {
        #pragma unroll
        for (int nt = 0; nt < 4; ++nt) {
            const size_t boff = (size_t)(n0 + nt * 16 + ln) * 256 + k0 + lq * 8;
            Bhi[nt] = *(const short8*)&WThi[boff];
            Blo[nt] = *(const short8*)&WTlo[boff];
        }
    };
    auto convA = [&](float (&rw)[4][8]) {
        #pragma unroll
        for (int mt = 0; mt < 4; ++mt)
            #pragma unroll
            for (int j = 0; j < 8; ++j) {
                const unsigned short h = bf16_bits(rw[mt][j]);
                Ahi[mt][j] = (short)h;
                Alo[mt][j] = (short)bf16_bits(rw[mt][j] - bf16_val(h));
            }
    };
    auto mfmas = [&]() {
        #pragma unroll
        for (int nt = 0; nt < 4; ++nt)
            #pragma unroll
            for (int mt = 0; mt < 4; ++mt) {
                acc[mt][nt] = __builtin_amdgcn_mfma_f32_16x16x32_bf16(Ahi[mt], Bhi[nt], acc[mt][nt], 0, 0, 0);
                acc[mt][nt] = __builtin_amdgcn_mfma_f32_16x16x32_bf16(Ahi[mt], Blo[nt], acc[mt][nt], 0, 0, 0);
                acc[mt][nt] = __builtin_amdgcn_mfma_f32_16x16x32_bf16(Alo[mt], Bhi[nt], acc[mt][nt], 0, 0, 0);
            }
    };

    loadraw(rawA, 0);
    #pragma unroll 1
    for (int t = 0; t < 4; ++t) {
        const int k0 = t * 64;
        // even sub-step: compute k0, prefetch k0+32
        loadB(k0);
        loadraw(rawB, k0 + 32);
        convA(rawA);
        mfmas();
        // odd sub-step: compute k0+32, prefetch k0+64 (last wraps: harmless)
        loadB(k0 + 32);
        loadraw(rawA, (k0 + 64) & 255);
        convA(rawB);
        mfmas();
    }

    const int b = px0 >> 12;
    if (blockIdx.y < 4) {
        // hh channels n0..n0+63 -> transposed fp16 store
        #pragma unroll
        for (int nt = 0; nt < 4; ++nt) {
            const int c = n0 + nt * 16 + ln;
            const float bias = bh[c];
            #pragma unroll
            for (int mt = 0; mt < 4; ++mt) {
                half4 hv;
                #pragma unroll
                for (int r = 0; r < 4; ++r) hv[r] = (_Float16)(acc[mt][nt][r] + bias);
                const int npix = (px0 & (NN - 1)) + mt * 16 + lq * 4;
                *(half4*)&hhT[((size_t)(b * CC + c)) * NN + npix] = hv;
            }
        }
    } else {
        // f (nt 0,1), g (nt 2,3): d = (nt&1)*16 + ln
        #pragma unroll
        for (int nt = 0; nt < 4; ++nt) {
            const int d = (nt & 1) * 16 + ln;
            const float bias = (nt < 2) ? bf[d] : bg[d];
            _Float16* dst = (nt < 2) ? fbuf : gbuf;
            #pragma unroll
            for (int mt = 0; mt < 4; ++mt)
                #pragma unroll
                for (int r = 0; r < 4; ++r)
                    dst[(size_t)(px0 + mt * 16 + lq * 4 + r) * CKK + d] =
                        (_Float16)(acc[mt][nt][r] + bias);
        }
    }
}

// ---------------------------------------------------------------------------
// K2: MFMA flash attention -- EXACT round-1 kernel (measured 160.5 us,
// VGPR 108; channel/q splits and epilogue hi/lo split all regressed).
// Block = 64 q x 256 c of one batch; 4 waves. Per 64-key iter:
//   phase A: wave w computes S^T for ITS 16 keys x 64 q (4 MFMA, no dup),
//            exp -> fp16 P -> shared LDS tile (A-layout, pad-72, dbuf)
//   barrier (1/iter)
//   phase B: issue NEXT iter's Bh global loads (post-barrier), then PV
//            with THIS iter's Bh (register dbuf).
// Rowmax pass-1 identical-instruction trick keeps exp <= 1 (fp16-safe).
// ---------------------------------------------------------------------------
__global__ __launch_bounds__(256, 2) void attn_kernel(
    const _Float16* __restrict__ fbuf, const _Float16* __restrict__ gbuf,
    const _Float16* __restrict__ hhT, float* __restrict__ obuf)
{
    __shared__ _Float16 P[2][64 * 72];   // 18 KB, dbuf
    __shared__ float mxbuf[4][64];
    __shared__ float rsbuf[4][64];

    const int tid = threadIdx.x, w = tid >> 6, lane = tid & 63;
    const int ln = lane & 15, lq = lane >> 4;
    const int b  = blockIdx.x & 7;               // batch == XCD
    const int q0 = (blockIdx.x >> 3) * 64;
    const int cb = w * 64;                       // this wave's channel base

    const f32x4 zero = {0.f, 0.f, 0.f, 0.f};
    constexpr float LOG2E = 1.4426950408889634f;

    // persistent g B-frags: B[k=d][n=q]
    half8 Bg[4];
    #pragma unroll
    for (int qt = 0; qt < 4; ++qt)
        Bg[qt] = *(const half8*)&gbuf[(size_t)(b * NN + q0 + qt * 16 + ln) * CKK + lq * 8];

    // base pointers (advance by constants inside loops)
    const _Float16* fb = &fbuf[(size_t)(b * NN + w * 16 + ln) * CKK + lq * 8];
    const _Float16* hb = &hhT[((size_t)(b * CC + cb + ln)) * NN + lq * 8];

    // ---- pass 1: rowmax (wave w covers keys j0 + w*16 + 0..15), pipelined ----
    float mx[4];
    #pragma unroll
    for (int qt = 0; qt < 4; ++qt) mx[qt] = -1e30f;
    half8 Afc = *(const half8*)fb;
    #pragma unroll 1
    for (int j0 = 0; j0 < NN; j0 += 64) {
        const int jn = (j0 + 64 < NN) ? j0 + 64 : j0;
        const half8 Afn = *(const half8*)&fb[(size_t)jn * CKK];
        #pragma unroll
        for (int qt = 0; qt < 4; ++qt) {
            const f32x4 s = __builtin_amdgcn_mfma_f32_16x16x32_f16(Afc, Bg[qt], zero, 0, 0, 0);
            mx[qt] = fmaxf(mx[qt], fmaxf(fmaxf(s[0], s[1]), fmaxf(s[2], s[3])));
        }
        Afc = Afn;
    }
    #pragma unroll
    for (int qt = 0; qt < 4; ++qt) {
        mx[qt] = fmaxf(mx[qt], __shfl_xor(mx[qt], 16));
        mx[qt] = fmaxf(mx[qt], __shfl_xor(mx[qt], 32));
    }
    if (lane < 16) {
        #pragma unroll
        for (int qt = 0; qt < 4; ++qt) mxbuf[w][qt * 16 + ln] = mx[qt];
    }
    __syncthreads();
    float mk[4];   // per-lane: q = qt*16 + ln
    #pragma unroll
    for (int qt = 0; qt < 4; ++qt)
        mk[qt] = LOG2E * fmaxf(fmaxf(mxbuf[0][qt * 16 + ln], mxbuf[1][qt * 16 + ln]),
                               fmaxf(mxbuf[2][qt * 16 + ln], mxbuf[3][qt * 16 + ln]));

    // ---- main loop ----
    f32x4 O[4][4];     // [qt][ct]
    #pragma unroll
    for (int qt = 0; qt < 4; ++qt)
        #pragma unroll
        for (int ct = 0; ct < 4; ++ct) O[qt][ct] = zero;
    float psum[4] = {0.f, 0.f, 0.f, 0.f};

    // phase A: S^T -> exp -> P (LDS); identical MFMA to pass 1
    auto phaseA = [&](const half8& Af, _Float16* Pb) {
        #pragma unroll
        for (int qt = 0; qt < 4; ++qt) {
            const f32x4 s = __builtin_amdgcn_mfma_f32_16x16x32_f16(Af, Bg[qt], zero, 0, 0, 0);
            half4 ph;
            float ps = 0.f;
            #pragma unroll
            for (int r = 0; r < 4; ++r) {
                const float p = exp2f(fmaf(s[r], LOG2E, -mk[qt]));
                ps += p;
                ph[r] = (_Float16)p;
            }
            psum[qt] += ps;
            // P[q = qt*16+ln][key = w*16 + lq*4 + r]  (A-layout, pad 72)
            *(half4*)&Pb[(qt * 16 + ln) * 72 + w * 16 + lq * 4] = ph;
        }
    };

    // issue 8 global b128 loads of hhT B-frags for key block j0
    auto loadBh = [&](half8 (&Bh)[4][2], int j0) {
        #pragma unroll
        for (int ct = 0; ct < 4; ++ct)
            #pragma unroll
            for (int kh = 0; kh < 2; ++kh)
                Bh[ct][kh] = *(const half8*)&hb[(size_t)ct * 16 * NN + j0 + kh * 32];
    };

    // phase B: PV for this wave's 64 channels, K=64 via 2 K32 halves
    auto phaseB = [&](const half8 (&Bh)[4][2], const _Float16* Pb) {
        __builtin_amdgcn_s_setprio(1);
        #pragma unroll
        for (int qt = 0; qt < 4; ++qt) {
            const half8 Ap0 = *(const half8*)&Pb[(qt * 16 + ln) * 72 + lq * 8];
            const half8 Ap1 = *(const half8*)&Pb[(qt * 16 + ln) * 72 + 32 + lq * 8];
            #pragma unroll
            for (int ct = 0; ct < 4; ++ct) {
                O[qt][ct] = __builtin_amdgcn_mfma_f32_16x16x32_f16(Ap0, Bh[ct][0], O[qt][ct], 0, 0, 0);
                O[qt][ct] = __builtin_amdgcn_mfma_f32_16x16x32_f16(Ap1, Bh[ct][1], O[qt][ct], 0, 0, 0);
            }
        }
        __builtin_amdgcn_s_setprio(0);
    };

    // prologue: current-iter buffers
    half8 Bh0[4][2], Bh1[4][2];
    half8 Af0, Af1;
    loadBh(Bh0, 0);
    Af0 = *(const half8*)fb;

    #pragma unroll 1
    for (int j0 = 0; j0 < NN; j0 += 128) {
        // --- even 64-key block: uses Bh0/Af0, prefetches Bh1/Af1 ---
        phaseA(Af0, P[0]);
        __syncthreads();                         // drains Bh0 (issued 1 iter ago)
        loadBh(Bh1, j0 + 64);                    // post-barrier issue: lands during
        Af1 = *(const half8*)&fb[(size_t)(j0 + 64) * CKK];  // phaseB + next phaseA
        phaseB(Bh0, P[0]);
        // --- odd 64-key block: uses Bh1/Af1, prefetches Bh0/Af0 ---
        phaseA(Af1, P[1]);
        __syncthreads();
        if (j0 + 128 < NN) {
            loadBh(Bh0, j0 + 128);
            Af0 = *(const half8*)&fb[(size_t)(j0 + 128) * CKK];
        }
        phaseB(Bh1, P[1]);
    }

    // ---- rowsum merge across waves ----
    #pragma unroll
    for (int qt = 0; qt < 4; ++qt) {
        psum[qt] += __shfl_xor(psum[qt], 16);
        psum[qt] += __shfl_xor(psum[qt], 32);
    }
    if (lane < 16) {
        #pragma unroll
        for (int qt = 0; qt < 4; ++qt) rsbuf[w][qt * 16 + ln] = psum[qt];
    }
    __syncthreads();

    // ---- epilogue: normalize, store (row-indexed q) ----
    #pragma unroll
    for (int qt = 0; qt < 4; ++qt)
        #pragma unroll
        for (int r = 0; r < 4; ++r) {
            const int q = qt * 16 + lq * 4 + r;
            const float rinv = 1.0f / (rsbuf[0][q] + rsbuf[1][q] + rsbuf[2][q] + rsbuf[3][q]);
            #pragma unroll
            for (int ct = 0; ct < 4; ++ct)
                obuf[((size_t)(b * NN + q0 + q)) * CC + cb + ct * 16 + ln] = O[qt][ct][r] * rinv;
        }
}

// ---------------------------------------------------------------------------
// K3: out = gamma * (o @ Wo + bo) + x  as tiled GEMM [32768x256]@[256x256].
// Same software-pipelined k-loop as fgh_kernel. Grid 128 x 4.
// ---------------------------------------------------------------------------
__global__ __launch_bounds__(256) void out_kernel(
    const float* __restrict__ obuf,
    const unsigned short* __restrict__ WThi, const unsigned short* __restrict__ WTlo,
    const float* __restrict__ bo, const float* __restrict__ gamma,
    const float* __restrict__ x, float* __restrict__ out)
{
    const int tid = threadIdx.x, w = tid >> 6, lane = tid & 63;
    const int ln = lane & 15, lq = lane >> 4;
    const int px0 = blockIdx.x * 256 + w * 64;
    const int n0  = blockIdx.y * 64;

    f32x4 acc[4][4];
    #pragma unroll
    for (int i = 0; i < 4; ++i)
        #pragma unroll
        for (int j = 0; j < 4; ++j) acc[i][j] = {0.f, 0.f, 0.f, 0.f};

    float  rawA[4][8], rawB[4][8];
    short8 Ahi[4], Alo[4], Bhi[4], Blo[4];

    auto loadraw = [&](float (&rw)[4][8], int k0) {
        #pragma unroll
        for (int mt = 0; mt < 4; ++mt) {
            const float* op = &obuf[(size_t)(px0 + mt * 16 + ln) * CC + k0 + lq * 8];
            *(float4*)&rw[mt][0] = *(const float4*)op;
            *(float4*)&rw[mt][4] = *(const float4*)(op + 4);
        }
    };
    auto loadB = [&](int k0) {
        #pragma unroll
        for (int nt = 0; nt < 4; ++nt) {
            const size_t boff = (size_t)(320 + n0 + nt * 16 + ln) * 256 + k0 + lq * 8;
            Bhi[nt] = *(const short8*)&WThi[boff];
            Blo[nt] = *(const short8*)&WTlo[boff];
        }
    };
    auto convA = [&](float (&rw)[4][8]) {
        #pragma unroll
        for (int mt = 0; mt < 4; ++mt)
            #pragma unroll
            for (int j = 0; j < 8; ++j) {
                const unsigned short h = bf16_bits(rw[mt][j]);
                Ahi[mt][j] = (short)h;
                Alo[mt][j] = (short)bf16_bits(rw[mt][j] - bf16_val(h));
            }
    };
    auto mfmas = [&]() {
        #pragma unroll
        for (int nt = 0; nt < 4; ++nt)
            #pragma unroll
            for (int mt = 0; mt < 4; ++mt) {
                acc[mt][nt] = __builtin_amdgcn_mfma_f32_16x16x32_bf16(Ahi[mt], Bhi[nt], acc[mt][nt], 0, 0, 0);
                acc[mt][nt] = __builtin_amdgcn_mfma_f32_16x16x32_bf16(Ahi[mt], Blo[nt], acc[mt][nt], 0, 0, 0);
                acc[mt][nt] = __builtin_amdgcn_mfma_f32_16x16x32_bf16(Alo[mt], Bhi[nt], acc[mt][nt], 0, 0, 0);
            }
    };

    loadraw(rawA, 0);
    #pragma unroll 1
    for (int t = 0; t < 4; ++t) {
        const int k0 = t * 64;
        loadB(k0);
        loadraw(rawB, k0 + 32);
        convA(rawA);
        mfmas();
        loadB(k0 + 32);
        loadraw(rawA, (k0 + 64) & 255);
        convA(rawB);
        mfmas();
    }

    const float gm = gamma[0];
    #pragma unroll
    for (int nt = 0; nt < 4; ++nt) {
        const int c = n0 + nt * 16 + ln;
        const float bias = bo[c];
        #pragma unroll
        for (int mt = 0; mt < 4; ++mt)
            #pragma unroll
            for (int r = 0; r < 4; ++r) {
                const size_t idx = (size_t)(px0 + mt * 16 + lq * 4 + r) * CC + c;
                out[idx] = gm * (acc[mt][nt][r] + bias) + x[idx];
            }
    }
}

// ---------------------------------------------------------------------------
extern "C" void kernel_launch(void* const* d_in, const int* in_sizes, int n_in,
                              void* d_out, int out_size, void* d_ws, size_t ws_size,
                              hipStream_t stream)
{
    (void)in_sizes; (void)n_in; (void)out_size; (void)ws_size;

    const float* x     = (const float*)d_in[0];
    const float* Wf    = (const float*)d_in[1];
    const float* bf    = (const float*)d_in[2];
    const float* Wg    = (const float*)d_in[3];
    const float* bg    = (const float*)d_in[4];
    const float* Wh    = (const float*)d_in[5];
    const float* bh    = (const float*)d_in[6];
    const float* Wo    = (const float*)d_in[7];
    const float* bo    = (const float*)d_in[8];
    const float* gamma = (const float*)d_in[9];
    float* out = (float*)d_out;

    // ws: f(2MB) | g(2MB) | hhT(16MB) | o(32MB) | WThi | WTlo (~0.6MB)
    _Float16* fbuf = (_Float16*)d_ws;
    _Float16* gbuf = fbuf + (size_t)BB * NN * CKK;
    _Float16* hhT  = gbuf + (size_t)BB * NN * CKK;
    float*    obuf = (float*)(hhT + (size_t)BB * CC * NN);
    unsigned short* WThi = (unsigned short*)(obuf + (size_t)BB * NN * CC);
    unsigned short* WTlo = WThi + (size_t)576 * 256;

    prep_kernel<<<576, 256, 0, stream>>>(Wf, Wg, Wh, Wo, WThi, WTlo);
    fgh_kernel<<<dim3(BB * NN / 256, 5), 256, 0, stream>>>(x, WThi, WTlo, bf, bg, bh,
                                                           fbuf, gbuf, hhT);
    attn_kernel<<<BB * NN / 64, 256, 0, stream>>>(fbuf, gbuf, hhT, obuf);
    out_kernel<<<dim3(BB * NN / 256, 4), 256, 0, stream>>>(obuf, WThi, WTlo, bo, gamma, x, out);
}